// Round 1
// baseline (14496.188 us; speedup 1.0000x reference)
//
#include <hip/hip_runtime.h>
#include <cstdint>
#include <cstddef>

#define B_   64
#define NP1  1025
#define N_   1024
#define D_   256
#define DP1  257
#define L_   4
#define H_   4
#define NPAD 1088   // padded token count (n and m), multiple of 64
#define IPAD 272    // padded output feature dim (257 -> 17*16)

typedef __bf16 bf16;
typedef bf16 bf16x8 __attribute__((ext_vector_type(8)));
typedef float f32x4 __attribute__((ext_vector_type(4)));

__device__ __forceinline__ f32x4 mfma16(bf16x8 a, bf16x8 b, f32x4 c) {
    return __builtin_amdgcn_mfma_f32_16x16x32_bf16(a, b, c, 0, 0, 0);
}

// ---------------------------------------------------------------------------
// Pb[l,h,i,j] = bf16(P[l,h,i,j]);  Qt[l,h,j,i] = bf16(Q[l,h,i,j])
// ---------------------------------------------------------------------------
__global__ void k_prep_pq(const float* __restrict__ ap,
                          bf16* __restrict__ Pb, bf16* __restrict__ Qt) {
    int idx = blockIdx.x * 256 + threadIdx.x;   // total = L*H*D*D = 1048576
    int j  = idx & 255;
    int i  = (idx >> 8) & 255;
    int lh = idx >> 16;                          // 0..15
    const float* base = ap + (size_t)lh * 2 * D_ * D_;
    float p = base[i * D_ + j];
    float q = base[D_ * D_ + i * D_ + j];
    Pb[((size_t)lh * D_ + i) * D_ + j] = (bf16)p;
    Qt[((size_t)lh * D_ + j) * D_ + i] = (bf16)q;
}

// ---------------------------------------------------------------------------
// Zb[b,n,i] = bf16(Z[b,n,i]) for n<1025 else 0   (i < 256 only)
// ---------------------------------------------------------------------------
__global__ void k_z2b(const float* __restrict__ Z, bf16* __restrict__ Zb) {
    int n = blockIdx.x, b = blockIdx.y, i = threadIdx.x;
    float v = 0.f;
    if (n < NP1) v = Z[((size_t)b * NP1 + n) * DP1 + i];
    Zb[((size_t)b * NPAD + n) * D_ + i] = (bf16)v;
}

// ---------------------------------------------------------------------------
// KT[b,h,i,m] = sum_j P[l,h,i,j] * Z[b,m,j]   (i<256), zero for m>=1024
// D[i][m] = A(P rows i) x B(Zb rows m)
// ---------------------------------------------------------------------------
__global__ __launch_bounds__(256) void k_kt(const bf16* __restrict__ Zb,
                                            const bf16* __restrict__ Pb,
                                            bf16* __restrict__ KT, int layer) {
    int tid = threadIdx.x;
    int wave = tid >> 6, lane = tid & 63, quad = lane >> 4, l16 = lane & 15;
    int mt = blockIdx.x, it = blockIdx.y, bh = blockIdx.z;
    int b = bh >> 2, h = bh & 3;
    int i0 = it * 64 + wave * 16;
    int m0 = mt * 64;

    const bf16* Prow = Pb + ((size_t)(layer * H_ + h) * D_ + (i0 + l16)) * D_ + quad * 8;
    bf16x8 a[8];
#pragma unroll
    for (int k = 0; k < 8; k++) a[k] = *(const bf16x8*)(Prow + k * 32);

    const bf16* Zbb = Zb + (size_t)b * NPAD * D_;
    f32x4 c[4];
#pragma unroll
    for (int s = 0; s < 4; s++) c[s] = (f32x4){0.f, 0.f, 0.f, 0.f};

#pragma unroll
    for (int s = 0; s < 4; s++) {
        const bf16* brow = Zbb + (size_t)(m0 + s * 16 + l16) * D_ + quad * 8;
#pragma unroll
        for (int k = 0; k < 8; k++)
            c[s] = mfma16(a[k], *(const bf16x8*)(brow + k * 32), c[s]);
    }

    bf16* KTbh = KT + (size_t)(b * H_ + h) * IPAD * NPAD;
#pragma unroll
    for (int s = 0; s < 4; s++) {
        int m = m0 + s * 16 + l16;
#pragma unroll
        for (int r = 0; r < 4; r++) {
            float v = (m < N_) ? c[s][r] : 0.f;   // mask last token + padding
            KTbh[(size_t)(i0 + quad * 4 + r) * NPAD + m] = (bf16)v;
        }
    }
}

// ---------------------------------------------------------------------------
// KT rows 256..271: row 256 = Z[b,m,256] (masked), rows 257..271 = 0
// ---------------------------------------------------------------------------
__global__ void k_kt_extra(const float* __restrict__ Z, bf16* __restrict__ KT) {
    int m = blockIdx.x * 256 + threadIdx.x;
    int b = blockIdx.y;
    if (m >= NPAD) return;
    float v = (m < N_) ? Z[((size_t)b * NP1 + m) * DP1 + D_] : 0.f;
    bf16 bv = (bf16)v;
#pragma unroll
    for (int h = 0; h < H_; h++) {
        bf16* row = KT + ((size_t)(b * H_ + h) * IPAD + D_) * NPAD + m;
        row[0] = bv;
#pragma unroll
        for (int r = 1; r < 16; r++) row[(size_t)r * NPAD] = (bf16)0.f;
    }
}

// ---------------------------------------------------------------------------
// Fused attention: per block (b, n-tile of 64). Wave w owns rows n0..n0+15.
// For each head: ZQ tile (MFMA, LDS round-trip), then loop m-chunks:
//   S = relu(ZQ . Zb^T), LDS round-trip, acc += S . KT^T
// Epilogue: Z += acc / N
// ---------------------------------------------------------------------------
__global__ __launch_bounds__(256) void k_attn(const bf16* __restrict__ Zb,
                                              const bf16* __restrict__ KT,
                                              const bf16* __restrict__ Qt,
                                              float* __restrict__ Z, int layer) {
    __shared__ bf16 zq[4][16][264];  // per-wave ZQ tile, +8 pad -> 2-way conflicts only
    __shared__ bf16 sl[4][16][40];   // per-wave S tile, +8 pad

    int tid = threadIdx.x;
    int wave = tid >> 6, lane = tid & 63, quad = lane >> 4, l16 = lane & 15;
    int nt = blockIdx.x, b = blockIdx.y;
    int n0 = nt * 64 + wave * 16;

    const bf16* Zbb = Zb + (size_t)b * NPAD * D_;

    f32x4 acc[17];
#pragma unroll
    for (int i = 0; i < 17; i++) acc[i] = (f32x4){0.f, 0.f, 0.f, 0.f};

    for (int h = 0; h < H_; h++) {
        // ---- ZQ stage: ZQ[n,j] = sum_i Zb[n,i] * Q[i,j], write to zq LDS ----
        bf16x8 az[8];
        {
            const bf16* arow = Zbb + (size_t)(n0 + l16) * D_ + quad * 8;
#pragma unroll
            for (int k = 0; k < 8; k++) az[k] = *(const bf16x8*)(arow + k * 32);
        }
        const bf16* Qth = Qt + (size_t)(layer * H_ + h) * D_ * D_;
        for (int j0 = 0; j0 < 256; j0 += 16) {
            f32x4 c = (f32x4){0.f, 0.f, 0.f, 0.f};
            const bf16* brow = Qth + (size_t)(j0 + l16) * D_ + quad * 8;
#pragma unroll
            for (int k = 0; k < 8; k++)
                c = mfma16(az[k], *(const bf16x8*)(brow + k * 32), c);
#pragma unroll
            for (int r = 0; r < 4; r++)
                zq[wave][quad * 4 + r][j0 + l16] = (bf16)c[r];
        }
        // read back in A-operand layout (same-wave LDS ops are in order)
        bf16x8 as_[8];
#pragma unroll
        for (int k = 0; k < 8; k++)
            as_[k] = *(const bf16x8*)(&zq[wave][l16][k * 32 + quad * 8]);

        const bf16* KTbh = KT + (size_t)(b * H_ + h) * IPAD * NPAD;

        for (int mc = 0; mc < NPAD / 32; mc++) {
            int m0 = mc * 32;
            // ---- S tiles: S[n,m] = sum_i ZQ[n,i] Zb[m,i] ----
            f32x4 s0 = (f32x4){0.f, 0.f, 0.f, 0.f};
            f32x4 s1 = (f32x4){0.f, 0.f, 0.f, 0.f};
            const bf16* br0 = Zbb + (size_t)(m0 + l16) * D_ + quad * 8;
            const bf16* br1 = br0 + 16 * D_;
#pragma unroll
            for (int k = 0; k < 8; k++) {
                s0 = mfma16(as_[k], *(const bf16x8*)(br0 + k * 32), s0);
                s1 = mfma16(as_[k], *(const bf16x8*)(br1 + k * 32), s1);
            }
            // relu + round-trip to A layout
#pragma unroll
            for (int r = 0; r < 4; r++) {
                float v0 = s0[r] > 0.f ? s0[r] : 0.f;
                float v1 = s1[r] > 0.f ? s1[r] : 0.f;
                sl[wave][quad * 4 + r][l16]      = (bf16)v0;
                sl[wave][quad * 4 + r][l16 + 16] = (bf16)v1;
            }
            bf16x8 a2 = *(const bf16x8*)(&sl[wave][l16][quad * 8]);
            // ---- acc[n,i] += S[n,m] * KT[i,m] ----
            const bf16* kr = KTbh + (size_t)l16 * NPAD + m0 + quad * 8;
#pragma unroll
            for (int itile = 0; itile < 17; itile++) {
                bf16x8 bk = *(const bf16x8*)(kr + (size_t)(itile * 16) * NPAD);
                acc[itile] = mfma16(a2, bk, acc[itile]);
            }
        }
    }

    // ---- epilogue: Z += acc / N ----
    const float inv = 1.0f / (float)N_;
#pragma unroll
    for (int itile = 0; itile < 17; itile++) {
#pragma unroll
        for (int r = 0; r < 4; r++) {
            int n = n0 + quad * 4 + r;
            int i = itile * 16 + l16;
            if (n < NP1 && i < DP1) {
                size_t idx = ((size_t)b * NP1 + n) * DP1 + i;
                Z[idx] += acc[itile][r] * inv;
            }
        }
    }
}

// ---------------------------------------------------------------------------
extern "C" void kernel_launch(void* const* d_in, const int* in_sizes, int n_in,
                              void* d_out, int out_size, void* d_ws, size_t ws_size,
                              hipStream_t stream) {
    const float* Zin = (const float*)d_in[0];
    const float* ap  = (const float*)d_in[1];
    float* Z = (float*)d_out;

    char* ws = (char*)d_ws;
    const size_t sz_Zb = (size_t)B_ * NPAD * D_ * sizeof(bf16);            // 35,651,584
    const size_t sz_KT = (size_t)B_ * H_ * IPAD * NPAD * sizeof(bf16);     // 151,519,232
    const size_t sz_P  = (size_t)L_ * H_ * D_ * D_ * sizeof(bf16);         // 2,097,152
    bf16* Zb = (bf16*)ws;
    bf16* KT = (bf16*)(ws + sz_Zb);
    bf16* Pb = (bf16*)(ws + sz_Zb + sz_KT);
    bf16* Qt = (bf16*)(ws + sz_Zb + sz_KT + sz_P);

    // Z working copy lives in d_out (fp32), updated in place per layer
    hipMemcpyAsync(Z, Zin, (size_t)B_ * NP1 * DP1 * sizeof(float),
                   hipMemcpyDeviceToDevice, stream);

    k_prep_pq<<<dim3((L_ * H_ * D_ * D_) / 256), 256, 0, stream>>>(ap, Pb, Qt);

    for (int l = 0; l < L_; l++) {
        k_z2b<<<dim3(NPAD, B_), 256, 0, stream>>>(Z, Zb);
        k_kt<<<dim3(NPAD / 64, D_ / 64, B_ * H_), 256, 0, stream>>>(Zb, Pb, KT, l);
        k_kt_extra<<<dim3((NPAD + 255) / 256, B_), 256, 0, stream>>>(Z, KT);
        k_attn<<<dim3(NPAD / 64, B_), 256, 0, stream>>>(Zb, KT, Qt, Z, l);
    }
}

// Round 2
// 9045.329 us; speedup vs baseline: 1.6026x; 1.6026x over previous
//
#include <hip/hip_runtime.h>
#include <cstdint>
#include <cstddef>

#define B_    64
#define NP1   1025
#define N_    1024
#define D_    256
#define DP1   257
#define L_    4
#define H_    4
#define NPAD  1088   // m dimension (KT width), 34 chunks of 32
#define NROWS 1152   // Zb row allocation: 9 blocks x 128 n-rows
#define IPAD  272    // padded output feature dim (257 -> 17*16)

typedef __bf16 bf16;
typedef bf16 bf16x8 __attribute__((ext_vector_type(8)));
typedef float f32x4 __attribute__((ext_vector_type(4)));

__device__ __forceinline__ f32x4 mfma16(bf16x8 a, bf16x8 b, f32x4 c) {
    return __builtin_amdgcn_mfma_f32_16x16x32_bf16(a, b, c, 0, 0, 0);
}

__device__ __forceinline__ void async16(const void* g, void* l) {
    __builtin_amdgcn_global_load_lds(
        (const __attribute__((address_space(1))) void*)g,
        (__attribute__((address_space(3))) void*)l, 16, 0, 0);
}

// ---------------------------------------------------------------------------
__global__ void k_prep_pq(const float* __restrict__ ap,
                          bf16* __restrict__ Pb, bf16* __restrict__ Qt) {
    int idx = blockIdx.x * 256 + threadIdx.x;   // L*H*D*D = 1048576
    int j  = idx & 255;
    int i  = (idx >> 8) & 255;
    int lh = idx >> 16;
    const float* base = ap + (size_t)lh * 2 * D_ * D_;
    float p = base[i * D_ + j];
    float q = base[D_ * D_ + i * D_ + j];
    Pb[((size_t)lh * D_ + i) * D_ + j] = (bf16)p;
    Qt[((size_t)lh * D_ + j) * D_ + i] = (bf16)q;   // Qt[j][i] = Q[i][j]
}

// ---------------------------------------------------------------------------
__global__ void k_z2b(const float* __restrict__ Z, bf16* __restrict__ Zb) {
    int n = blockIdx.x, b = blockIdx.y, i = threadIdx.x;
    float v = 0.f;
    if (n < NP1) v = Z[((size_t)b * NP1 + n) * DP1 + i];
    Zb[((size_t)b * NROWS + n) * D_ + i] = (bf16)v;
}

// ---------------------------------------------------------------------------
// KT[b,h,i,m] = sum_j P[l,h,i,j] * Zb[b,m,j], zero for m>=1024
// ---------------------------------------------------------------------------
__global__ __launch_bounds__(256) void k_kt(const bf16* __restrict__ Zb,
                                            const bf16* __restrict__ Pb,
                                            bf16* __restrict__ KT, int layer) {
    int tid = threadIdx.x;
    int wave = tid >> 6, lane = tid & 63, quad = lane >> 4, l16 = lane & 15;
    int mt = blockIdx.x, it = blockIdx.y, bh = blockIdx.z;
    int b = bh >> 2, h = bh & 3;
    int i0 = it * 64 + wave * 16;
    int m0 = mt * 64;

    const bf16* Prow = Pb + ((size_t)(layer * H_ + h) * D_ + (i0 + l16)) * D_ + quad * 8;
    bf16x8 a[8];
#pragma unroll
    for (int k = 0; k < 8; k++) a[k] = *(const bf16x8*)(Prow + k * 32);

    const bf16* Zbb = Zb + (size_t)b * NROWS * D_;
    f32x4 c[4];
#pragma unroll
    for (int s = 0; s < 4; s++) c[s] = (f32x4){0.f, 0.f, 0.f, 0.f};

#pragma unroll
    for (int s = 0; s < 4; s++) {
        const bf16* brow = Zbb + (size_t)(m0 + s * 16 + l16) * D_ + quad * 8;
#pragma unroll
        for (int k = 0; k < 8; k++)
            c[s] = mfma16(a[k], *(const bf16x8*)(brow + k * 32), c[s]);
    }

    bf16* KTbh = KT + (size_t)(b * H_ + h) * IPAD * NPAD;
#pragma unroll
    for (int s = 0; s < 4; s++) {
        int m = m0 + s * 16 + l16;
#pragma unroll
        for (int r = 0; r < 4; r++) {
            float v = (m < N_) ? c[s][r] : 0.f;
            KTbh[(size_t)(i0 + quad * 4 + r) * NPAD + m] = (bf16)v;
        }
    }
}

// ---------------------------------------------------------------------------
__global__ void k_kt_extra(const float* __restrict__ Z, bf16* __restrict__ KT) {
    int m = blockIdx.x * 256 + threadIdx.x;
    int b = blockIdx.y;
    if (m >= NPAD) return;
    float v = (m < N_) ? Z[((size_t)b * NP1 + m) * DP1 + D_] : 0.f;
    bf16 bv = (bf16)v;
#pragma unroll
    for (int h = 0; h < H_; h++) {
        bf16* row = KT + ((size_t)(b * H_ + h) * IPAD + D_) * NPAD + m;
        row[0] = bv;
#pragma unroll
        for (int r = 1; r < 16; r++) row[(size_t)r * NPAD] = (bf16)0.f;
    }
}

// ---------------------------------------------------------------------------
// Fused flash attention, v2: block = 128 n-rows x 272 i, 4 waves x 32 rows.
// LDS-staged (global_load_lds, XOR-swizzled, double-buffered) Zb/KT chunks.
// ---------------------------------------------------------------------------
__global__ __launch_bounds__(256, 2) void k_attn(const bf16* __restrict__ Zb,
                                                 const bf16* __restrict__ KT,
                                                 const bf16* __restrict__ Qt,
                                                 float* __restrict__ Z, int layer) {
    // LDS[r][c] holds global chunk (c ^ f(r)) of row r  (16B chunks)
    __shared__ bf16 zbS[2][32][256];   // f(r) = r&7      (32 chunks/row)
    __shared__ bf16 ktS[2][IPAD][32];  // f(r) = (r>>1)&3 (4 chunks/row)
    __shared__ bf16 sl[4][32][40];     // per-wave roundtrip, 80B rows (5-slot walk)

    const int tid  = threadIdx.x;
    const int wave = tid >> 6, lane = tid & 63;
    const int quad = lane >> 4, l16 = lane & 15;
    const int bx = blockIdx.x, b = blockIdx.y;
    const int n0w = bx * 128 + wave * 32;

    const bf16* Zbb = Zb + (size_t)b * NROWS * D_;

    // staging lane roles (constant across iters)
    const int zrow  = wave * 2 + (lane >> 5);                 // +t*8
    const int zscol = ((lane & 31) ^ (zrow & 7)) * 8;         // elem offset
    const int krow  = wave * 16 + (lane >> 2);                // +t*64
    const int kscol = ((lane & 3) ^ ((lane >> 3) & 3)) * 8;
    const int xs    = l16 & 7;           // S-read swizzle
    const int kf    = (l16 >> 1) & 3;    // PV-read swizzle

    f32x4 acc[2][17];
#pragma unroll
    for (int ns = 0; ns < 2; ns++)
#pragma unroll
        for (int it = 0; it < 17; it++) acc[ns][it] = (f32x4){0.f, 0.f, 0.f, 0.f};

    for (int h = 0; h < H_; h++) {
        const bf16* Qth  = Qt + (size_t)(layer * H_ + h) * D_ * D_;
        const bf16* KTbh = KT + (size_t)(b * H_ + h) * IPAD * NPAD;

        // ---- phase 1: ZQ for this wave's 32 rows -> zqa A-frags ----
        bf16x8 zqa[2][8];
#pragma unroll 2
        for (int jc = 0; jc < 8; jc++) {
            f32x4 c[2][2];
#pragma unroll
            for (int jt = 0; jt < 2; jt++)
#pragma unroll
                for (int ns = 0; ns < 2; ns++) c[jt][ns] = (f32x4){0.f, 0.f, 0.f, 0.f};
#pragma unroll
            for (int kc = 0; kc < 8; kc++) {
                bf16x8 azc[2];
#pragma unroll
                for (int ns = 0; ns < 2; ns++)
                    azc[ns] = *(const bf16x8*)(Zbb + (size_t)(n0w + ns * 16 + l16) * D_
                                               + kc * 32 + quad * 8);
#pragma unroll
                for (int jt = 0; jt < 2; jt++) {
                    bf16x8 qb = *(const bf16x8*)(Qth + (size_t)(jc * 32 + jt * 16 + l16) * D_
                                                 + kc * 32 + quad * 8);
#pragma unroll
                    for (int ns = 0; ns < 2; ns++)
                        c[jt][ns] = mfma16(azc[ns], qb, c[jt][ns]);
                }
            }
#pragma unroll
            for (int jt = 0; jt < 2; jt++)
#pragma unroll
                for (int ns = 0; ns < 2; ns++)
#pragma unroll
                    for (int r = 0; r < 4; r++)
                        sl[wave][ns * 16 + quad * 4 + r][jt * 16 + l16] = (bf16)c[jt][ns][r];
#pragma unroll
            for (int ns = 0; ns < 2; ns++)
                zqa[ns][jc] = *(const bf16x8*)(&sl[wave][ns * 16 + l16][quad * 8]);
        }

        // ---- main loop over m-chunks of 32, double-buffered staging ----
        auto stage = [&](int mc_, int p_) {
            int m0 = mc_ * 32;
            const bf16* zsrc = Zbb + (size_t)(m0 + zrow) * D_ + zscol;
#pragma unroll
            for (int t = 0; t < 4; t++)
                async16(zsrc + (size_t)t * 8 * D_, &zbS[p_][t * 8 + wave * 2][0]);
            const bf16* ksrc = KTbh + (size_t)krow * NPAD + m0 + kscol;
#pragma unroll
            for (int t = 0; t < 4; t++)
                async16(ksrc + (size_t)t * 64 * NPAD, &ktS[p_][t * 64 + wave * 16][0]);
            if (wave == 0)
                async16(ksrc + (size_t)256 * NPAD, &ktS[p_][256][0]);
        };

        stage(0, 0);
        __syncthreads();

        for (int mc = 0; mc < NPAD / 32; mc++) {
            int p = mc & 1;
            if (mc + 1 < NPAD / 32) stage(mc + 1, p ^ 1);

            // ---- S = relu(ZQ . Zb_chunk^T): 2 n-sub x 2 m-tiles ----
            f32x4 s[2][2];
#pragma unroll
            for (int ns = 0; ns < 2; ns++)
#pragma unroll
                for (int mt = 0; mt < 2; mt++) s[ns][mt] = (f32x4){0.f, 0.f, 0.f, 0.f};
#pragma unroll
            for (int mt = 0; mt < 2; mt++) {
                const bf16* zr = &zbS[p][mt * 16 + l16][0];
#pragma unroll
                for (int kc = 0; kc < 8; kc++) {
                    bf16x8 bz = *(const bf16x8*)(zr + (((kc * 4 + quad) ^ xs) * 8));
                    s[0][mt] = mfma16(zqa[0][kc], bz, s[0][mt]);
                    s[1][mt] = mfma16(zqa[1][kc], bz, s[1][mt]);
                }
            }
            // relu + LDS roundtrip to A layout
#pragma unroll
            for (int ns = 0; ns < 2; ns++)
#pragma unroll
                for (int mt = 0; mt < 2; mt++)
#pragma unroll
                    for (int r = 0; r < 4; r++) {
                        float v = s[ns][mt][r];
                        sl[wave][ns * 16 + quad * 4 + r][mt * 16 + l16] =
                            (bf16)(v > 0.f ? v : 0.f);
                    }
            bf16x8 a2[2];
#pragma unroll
            for (int ns = 0; ns < 2; ns++)
                a2[ns] = *(const bf16x8*)(&sl[wave][ns * 16 + l16][quad * 8]);

            // ---- acc += S . KT_chunk^T over all 17 i-tiles ----
#pragma unroll
            for (int it = 0; it < 17; it++) {
                const bf16* kr = &ktS[p][it * 16 + l16][0];
                bf16x8 bk = *(const bf16x8*)(kr + ((quad ^ kf) * 8));
                acc[0][it] = mfma16(a2[0], bk, acc[0][it]);
                acc[1][it] = mfma16(a2[1], bk, acc[1][it]);
            }
            __syncthreads();
        }
    }

    // ---- epilogue: Z += acc / N ----
    const float inv = 1.0f / (float)N_;
#pragma unroll
    for (int ns = 0; ns < 2; ns++)
#pragma unroll
        for (int it = 0; it < 17; it++)
#pragma unroll
            for (int r = 0; r < 4; r++) {
                int n = n0w + ns * 16 + quad * 4 + r;
                int i = it * 16 + l16;
                if (n < NP1 && i < DP1)
                    Z[((size_t)b * NP1 + n) * DP1 + i] += acc[ns][it][r] * inv;
            }
}

// ---------------------------------------------------------------------------
extern "C" void kernel_launch(void* const* d_in, const int* in_sizes, int n_in,
                              void* d_out, int out_size, void* d_ws, size_t ws_size,
                              hipStream_t stream) {
    const float* Zin = (const float*)d_in[0];
    const float* ap  = (const float*)d_in[1];
    float* Z = (float*)d_out;

    char* ws = (char*)d_ws;
    const size_t sz_Zb = (size_t)B_ * NROWS * D_ * sizeof(bf16);        // 37,748,736
    const size_t sz_KT = (size_t)B_ * H_ * IPAD * NPAD * sizeof(bf16);  // 151,519,232
    const size_t sz_P  = (size_t)L_ * H_ * D_ * D_ * sizeof(bf16);      // 2,097,152
    bf16* Zb = (bf16*)ws;
    bf16* KT = (bf16*)(ws + sz_Zb);
    bf16* Pb = (bf16*)(ws + sz_Zb + sz_KT);
    bf16* Qt = (bf16*)(ws + sz_Zb + sz_KT + sz_P);

    hipMemcpyAsync(Z, Zin, (size_t)B_ * NP1 * DP1 * sizeof(float),
                   hipMemcpyDeviceToDevice, stream);

    k_prep_pq<<<dim3((L_ * H_ * D_ * D_) / 256), 256, 0, stream>>>(ap, Pb, Qt);

    for (int l = 0; l < L_; l++) {
        k_z2b<<<dim3(NROWS, B_), 256, 0, stream>>>(Z, Zb);
        k_kt<<<dim3(NPAD / 64, D_ / 64, B_ * H_), 256, 0, stream>>>(Zb, Pb, KT, l);
        k_kt_extra<<<dim3((NPAD + 255) / 256, B_), 256, 0, stream>>>(Z, KT);
        k_attn<<<dim3(9, B_), 256, 0, stream>>>(Zb, KT, Qt, Z, l);
    }
}

// Round 3
// 7660.309 us; speedup vs baseline: 1.8924x; 1.1808x over previous
//
#include <hip/hip_runtime.h>
#include <cstdint>
#include <cstddef>

#define B_    64
#define NP1   1025
#define N_    1024
#define D_    256
#define DP1   257
#define L_    4
#define H_    4
#define NPAD  1088   // m dimension (KT width), 34 chunks of 32
#define NROWS 1152   // Zb row allocation: 9 blocks x 128 n-rows
#define IPAD  272    // padded output feature dim (257 -> 17*16)

typedef __bf16 bf16;
typedef bf16 bf16x8 __attribute__((ext_vector_type(8)));
typedef float f32x4 __attribute__((ext_vector_type(4)));

__device__ __forceinline__ f32x4 mfma16(bf16x8 a, bf16x8 b, f32x4 c) {
    return __builtin_amdgcn_mfma_f32_16x16x32_bf16(a, b, c, 0, 0, 0);
}

__device__ __forceinline__ void async16(const void* g, void* l) {
    __builtin_amdgcn_global_load_lds(
        (const __attribute__((address_space(1))) void*)g,
        (__attribute__((address_space(3))) void*)l, 16, 0, 0);
}

// ---------------------------------------------------------------------------
__global__ void k_prep_pq(const float* __restrict__ ap,
                          bf16* __restrict__ Pb, bf16* __restrict__ Qt) {
    int idx = blockIdx.x * 256 + threadIdx.x;   // L*H*D*D = 1048576
    int j  = idx & 255;
    int i  = (idx >> 8) & 255;
    int lh = idx >> 16;
    const float* base = ap + (size_t)lh * 2 * D_ * D_;
    float p = base[i * D_ + j];
    float q = base[D_ * D_ + i * D_ + j];
    Pb[((size_t)lh * D_ + i) * D_ + j] = (bf16)p;
    Qt[((size_t)lh * D_ + j) * D_ + i] = (bf16)q;   // Qt[j][i] = Q[i][j]
}

// ---------------------------------------------------------------------------
__global__ void k_z2b(const float* __restrict__ Z, bf16* __restrict__ Zb) {
    int n = blockIdx.x, b = blockIdx.y, i = threadIdx.x;
    float v = 0.f;
    if (n < NP1) v = Z[((size_t)b * NP1 + n) * DP1 + i];
    Zb[((size_t)b * NROWS + n) * D_ + i] = (bf16)v;
}

// ---------------------------------------------------------------------------
// KT[b,h,i,m] = sum_j P[l,h,i,j] * Zb[b,m,j], zero for m>=1024
// ---------------------------------------------------------------------------
__global__ __launch_bounds__(256) void k_kt(const bf16* __restrict__ Zb,
                                            const bf16* __restrict__ Pb,
                                            bf16* __restrict__ KT, int layer) {
    int tid = threadIdx.x;
    int wave = tid >> 6, lane = tid & 63, quad = lane >> 4, l16 = lane & 15;
    int mt = blockIdx.x, it = blockIdx.y, bh = blockIdx.z;
    int b = bh >> 2, h = bh & 3;
    int i0 = it * 64 + wave * 16;
    int m0 = mt * 64;

    const bf16* Prow = Pb + ((size_t)(layer * H_ + h) * D_ + (i0 + l16)) * D_ + quad * 8;
    bf16x8 a[8];
#pragma unroll
    for (int k = 0; k < 8; k++) a[k] = *(const bf16x8*)(Prow + k * 32);

    const bf16* Zbb = Zb + (size_t)b * NROWS * D_;
    f32x4 c[4];
#pragma unroll
    for (int s = 0; s < 4; s++) c[s] = (f32x4){0.f, 0.f, 0.f, 0.f};

#pragma unroll
    for (int s = 0; s < 4; s++) {
        const bf16* brow = Zbb + (size_t)(m0 + s * 16 + l16) * D_ + quad * 8;
#pragma unroll
        for (int k = 0; k < 8; k++)
            c[s] = mfma16(a[k], *(const bf16x8*)(brow + k * 32), c[s]);
    }

    bf16* KTbh = KT + (size_t)(b * H_ + h) * IPAD * NPAD;
#pragma unroll
    for (int s = 0; s < 4; s++) {
        int m = m0 + s * 16 + l16;
#pragma unroll
        for (int r = 0; r < 4; r++) {
            float v = (m < N_) ? c[s][r] : 0.f;
            KTbh[(size_t)(i0 + quad * 4 + r) * NPAD + m] = (bf16)v;
        }
    }
}

// ---------------------------------------------------------------------------
__global__ void k_kt_extra(const float* __restrict__ Z, bf16* __restrict__ KT) {
    int m = blockIdx.x * 256 + threadIdx.x;
    int b = blockIdx.y;
    if (m >= NPAD) return;
    float v = (m < N_) ? Z[((size_t)b * NP1 + m) * DP1 + D_] : 0.f;
    bf16 bv = (bf16)v;
#pragma unroll
    for (int h = 0; h < H_; h++) {
        bf16* row = KT + ((size_t)(b * H_ + h) * IPAD + D_) * NPAD + m;
        row[0] = bv;
#pragma unroll
        for (int r = 1; r < 16; r++) row[(size_t)r * NPAD] = (bf16)0.f;
    }
}

// ---------------------------------------------------------------------------
// Fused flash attention v3: XCD-swizzled grid, azc hoisted, head-boundary
// prefetch. Block = 128 n-rows x 272 i, 4 waves x 32 rows.
// ---------------------------------------------------------------------------
__global__ __launch_bounds__(256, 2) void k_attn(const bf16* __restrict__ Zb,
                                                 const bf16* __restrict__ KT,
                                                 const bf16* __restrict__ Qt,
                                                 float* __restrict__ Z, int layer) {
    __shared__ bf16 zbS[2][32][256];   // XOR-swizzled: f(r) = r&7
    __shared__ bf16 ktS[2][IPAD][32];  // f(r) = (r>>1)&3
    __shared__ bf16 sl[4][32][40];

    const int tid  = threadIdx.x;
    const int wave = tid >> 6, lane = tid & 63;
    const int quad = lane >> 4, l16 = lane & 15;

    // XCD swizzle: all 9 n-blocks of a given b on the same XCD (id & 7),
    // launched consecutively for temporal L2 locality.
    const int id  = blockIdx.x;
    const int xcd = id & 7, kk = id >> 3;     // kk in 0..71
    const int b   = xcd + 8 * (kk / 9);
    const int bx  = kk % 9;
    const int n0w = bx * 128 + wave * 32;

    const bf16* Zbb = Zb + (size_t)b * NROWS * D_;

    const int zrow  = wave * 2 + (lane >> 5);
    const int zscol = ((lane & 31) ^ (zrow & 7)) * 8;
    const int krow  = wave * 16 + (lane >> 2);
    const int kscol = ((lane & 3) ^ ((lane >> 3) & 3)) * 8;
    const int xs    = l16 & 7;
    const int kf    = (l16 >> 1) & 3;

    f32x4 acc[2][17];
#pragma unroll
    for (int ns = 0; ns < 2; ns++)
#pragma unroll
        for (int it = 0; it < 17; it++) acc[ns][it] = (f32x4){0.f, 0.f, 0.f, 0.f};

    for (int h = 0; h < H_; h++) {
        const bf16* Qth  = Qt + (size_t)(layer * H_ + h) * D_ * D_;
        const bf16* KTbh = KT + (size_t)(b * H_ + h) * IPAD * NPAD;

        // ---- phase 1: ZQ -> zqa A-frags (azc loaded ONCE per ns) ----
        bf16x8 zqa[2][8];
#pragma unroll
        for (int ns = 0; ns < 2; ns++) {
            bf16x8 azc[8];
            const bf16* arow = Zbb + (size_t)(n0w + ns * 16 + l16) * D_ + quad * 8;
#pragma unroll
            for (int kc = 0; kc < 8; kc++)
                azc[kc] = *(const bf16x8*)(arow + kc * 32);
#pragma unroll 2
            for (int jc = 0; jc < 8; jc++) {
                f32x4 c0 = (f32x4){0.f, 0.f, 0.f, 0.f};
                f32x4 c1 = (f32x4){0.f, 0.f, 0.f, 0.f};
#pragma unroll
                for (int kc = 0; kc < 8; kc++) {
                    const bf16* qb = Qth + (size_t)(jc * 32 + l16) * D_ + kc * 32 + quad * 8;
                    c0 = mfma16(azc[kc], *(const bf16x8*)(qb), c0);
                    c1 = mfma16(azc[kc], *(const bf16x8*)(qb + 16 * D_), c1);
                }
#pragma unroll
                for (int r = 0; r < 4; r++) {
                    sl[wave][ns * 16 + quad * 4 + r][l16]      = (bf16)c0[r];
                    sl[wave][ns * 16 + quad * 4 + r][16 + l16] = (bf16)c1[r];
                }
                zqa[ns][jc] = *(const bf16x8*)(&sl[wave][ns * 16 + l16][quad * 8]);
            }
        }

        auto stage = [&](int mc_, int p_, const bf16* ktbase) {
            int m0 = mc_ * 32;
            const bf16* zsrc = Zbb + (size_t)(m0 + zrow) * D_ + zscol;
#pragma unroll
            for (int t = 0; t < 4; t++)
                async16(zsrc + (size_t)t * 8 * D_, &zbS[p_][t * 8 + wave * 2][0]);
            const bf16* ksrc = ktbase + (size_t)krow * NPAD + m0 + kscol;
#pragma unroll
            for (int t = 0; t < 4; t++)
                async16(ksrc + (size_t)t * 64 * NPAD, &ktS[p_][t * 64 + wave * 16][0]);
            if (wave == 0)
                async16(ksrc + (size_t)256 * NPAD, &ktS[p_][256][0]);
        };

        if (h == 0) {
            stage(0, 0, KTbh);
            __syncthreads();
        }
        // for h>0: chunk 0 was prefetched into buffer 0 during h-1's last chunk

        for (int mc = 0; mc < NPAD / 32; mc++) {
            int p = mc & 1;
            if (mc + 1 < NPAD / 32)
                stage(mc + 1, p ^ 1, KTbh);
            else if (h + 1 < H_)
                stage(0, p ^ 1, KTbh + (size_t)IPAD * NPAD);  // next head, chunk 0

            // ---- S = relu(ZQ . Zb_chunk^T) ----
            f32x4 s[2][2];
#pragma unroll
            for (int ns = 0; ns < 2; ns++)
#pragma unroll
                for (int mt = 0; mt < 2; mt++) s[ns][mt] = (f32x4){0.f, 0.f, 0.f, 0.f};
#pragma unroll
            for (int mt = 0; mt < 2; mt++) {
                const bf16* zr = &zbS[p][mt * 16 + l16][0];
#pragma unroll
                for (int kc = 0; kc < 8; kc++) {
                    bf16x8 bz = *(const bf16x8*)(zr + (((kc * 4 + quad) ^ xs) * 8));
                    s[0][mt] = mfma16(zqa[0][kc], bz, s[0][mt]);
                    s[1][mt] = mfma16(zqa[1][kc], bz, s[1][mt]);
                }
            }
#pragma unroll
            for (int ns = 0; ns < 2; ns++)
#pragma unroll
                for (int mt = 0; mt < 2; mt++)
#pragma unroll
                    for (int r = 0; r < 4; r++) {
                        float v = s[ns][mt][r];
                        sl[wave][ns * 16 + quad * 4 + r][mt * 16 + l16] =
                            (bf16)(v > 0.f ? v : 0.f);
                    }
            bf16x8 a2[2];
#pragma unroll
            for (int ns = 0; ns < 2; ns++)
                a2[ns] = *(const bf16x8*)(&sl[wave][ns * 16 + l16][quad * 8]);

            // ---- acc += S . KT_chunk^T ----
#pragma unroll
            for (int it = 0; it < 17; it++) {
                const bf16* kr = &ktS[p][it * 16 + l16][0];
                bf16x8 bk = *(const bf16x8*)(kr + ((quad ^ kf) * 8));
                acc[0][it] = mfma16(a2[0], bk, acc[0][it]);
                acc[1][it] = mfma16(a2[1], bk, acc[1][it]);
            }
            __syncthreads();
        }
    }

    // ---- epilogue: Z += acc / N ----
    const float inv = 1.0f / (float)N_;
#pragma unroll
    for (int ns = 0; ns < 2; ns++)
#pragma unroll
        for (int it = 0; it < 17; it++)
#pragma unroll
            for (int r = 0; r < 4; r++) {
                int n = n0w + ns * 16 + quad * 4 + r;
                int i = it * 16 + l16;
                if (n < NP1 && i < DP1)
                    Z[((size_t)b * NP1 + n) * DP1 + i] += acc[ns][it][r] * inv;
            }
}

// ---------------------------------------------------------------------------
extern "C" void kernel_launch(void* const* d_in, const int* in_sizes, int n_in,
                              void* d_out, int out_size, void* d_ws, size_t ws_size,
                              hipStream_t stream) {
    const float* Zin = (const float*)d_in[0];
    const float* ap  = (const float*)d_in[1];
    float* Z = (float*)d_out;

    char* ws = (char*)d_ws;
    const size_t sz_Zb = (size_t)B_ * NROWS * D_ * sizeof(bf16);
    const size_t sz_KT = (size_t)B_ * H_ * IPAD * NPAD * sizeof(bf16);
    const size_t sz_P  = (size_t)L_ * H_ * D_ * D_ * sizeof(bf16);
    bf16* Zb = (bf16*)ws;
    bf16* KT = (bf16*)(ws + sz_Zb);
    bf16* Pb = (bf16*)(ws + sz_Zb + sz_KT);
    bf16* Qt = (bf16*)(ws + sz_Zb + sz_KT + sz_P);

    hipMemcpyAsync(Z, Zin, (size_t)B_ * NP1 * DP1 * sizeof(float),
                   hipMemcpyDeviceToDevice, stream);

    k_prep_pq<<<dim3((L_ * H_ * D_ * D_) / 256), 256, 0, stream>>>(ap, Pb, Qt);

    for (int l = 0; l < L_; l++) {
        k_z2b<<<dim3(NROWS, B_), 256, 0, stream>>>(Z, Zb);
        k_kt<<<dim3(NPAD / 64, D_ / 64, B_ * H_), 256, 0, stream>>>(Zb, Pb, KT, l);
        k_kt_extra<<<dim3((NPAD + 255) / 256, B_), 256, 0, stream>>>(Z, KT);
        k_attn<<<dim3(9 * B_), 256, 0, stream>>>(Zb, KT, Qt, Z, l);
    }
}